// Round 6
// baseline (342.017 us; speedup 1.0000x reference)
//
#include <hip/hip_runtime.h>

#define OUT_N 11008
#define IN_K  4096
#define BATCH 32
#define SEGS  8
#define KSEG  (IN_K / SEGS)   // 512 k per block
#define OPB   64              // outputs per block (4 waves x 16 rows)
#define XSTR  516             // xs row stride (shorts)

typedef __attribute__((ext_vector_type(8))) short short8;
typedef __attribute__((ext_vector_type(4))) float float4v;

// out[b][o] = bias[o]; main kernel atomically accumulates K-segment partials.
__global__ __launch_bounds__(256) void init_kernel(
    const float* __restrict__ bias, float* __restrict__ out)
{
    int i = blockIdx.x * 256 + threadIdx.x;
    if (i < BATCH * OUT_N) out[i] = bias[i % OUT_N];
}

// fp32 -> bf16 RNE
__device__ __forceinline__ unsigned short f2bf(float f) {
    unsigned u = __builtin_bit_cast(unsigned, f);
    unsigned r = u + 0x7FFFu + ((u >> 16) & 1u);
    return (unsigned short)(r >> 16);
}

// pack two fp32 (exact {-1,0,1}) into two bf16 by mantissa truncation
__device__ __forceinline__ unsigned pkbf16(float fhi, float flo) {
    return __builtin_amdgcn_perm(__builtin_bit_cast(unsigned, fhi),
                                 __builtin_bit_cast(unsigned, flo),
                                 0x07060302u);
}

// DIAGNOSTIC BUILD: the K-loop body executes twice (identical deterministic
// FP sequence -> acc is exactly 2x the partial), epilogue scales by 0.5.
// Purpose: push this kernel's duration above the harness's ~105us poison
// fills so it lands in the rocprof top-5 and we finally see its FETCH /
// hbm_gbps / VALUBusy / Occupancy. Remove the rep loop next round.
__global__ __launch_bounds__(256, 4) void lin2bit_kernel(
    const int* __restrict__ wq, const float* __restrict__ scale,
    const float* __restrict__ x, float* __restrict__ out)
{
    __shared__ unsigned short xs[BATCH][XSTR];   // 33024 B -> 4 blocks/CU

    const int t    = threadIdx.x;
    const int lane = t & 63;
    const int wave = t >> 6;
    const int kseg = blockIdx.y * KSEG;
    const int o0   = blockIdx.x * OPB;

    // --- stage x[0:32][kseg:+512] fp32 -> bf16 LDS (16 float4 per thread) ---
#pragma unroll
    for (int it = 0; it < 16; ++it) {
        int idx = it * 256 + t;
        int b   = idx >> 7;            // 128 float4 per row
        int k4  = idx & 127;
        float4 v = *reinterpret_cast<const float4*>(x + b * IN_K + kseg + k4 * 4);
        ushort4 h = { f2bf(v.x), f2bf(v.y), f2bf(v.z), f2bf(v.w) };
        *reinterpret_cast<ushort4*>(&xs[b][k4 * 4]) = h;
    }
    __syncthreads();

    const int quad = lane >> 4;
    const int l16  = lane & 15;
    const int o    = o0 + wave * 16 + l16;

    const int* __restrict__ wp = wq + (size_t)o * IN_K + kseg + quad * 8;
    const unsigned short* x0 = &xs[l16][quad * 8];
    const unsigned short* x1 = &xs[l16 + 16][quad * 8];

    float4v acc0 = {0.f, 0.f, 0.f, 0.f};
    float4v acc1 = {0.f, 0.f, 0.f, 0.f};

#pragma unroll 1
    for (int rep = 0; rep < 2; ++rep) {
#pragma unroll
        for (int ki = 0; ki < KSEG; ki += 32) {
            int4 w0 = *reinterpret_cast<const int4*>(wp + ki);
            int4 w1 = *reinterpret_cast<const int4*>(wp + ki + 4);
            uint4 bw;
            bw.x = pkbf16((float)w0.y, (float)w0.x);
            bw.y = pkbf16((float)w0.w, (float)w0.z);
            bw.z = pkbf16((float)w1.y, (float)w1.x);
            bw.w = pkbf16((float)w1.w, (float)w1.z);
            short8 bf = __builtin_bit_cast(short8, bw);
            short8 a0 = *reinterpret_cast<const short8*>(x0 + ki);
            short8 a1 = *reinterpret_cast<const short8*>(x1 + ki);
            acc0 = __builtin_amdgcn_mfma_f32_16x16x32_bf16(a0, bf, acc0, 0, 0, 0);
            acc1 = __builtin_amdgcn_mfma_f32_16x16x32_bf16(a1, bf, acc1, 0, 0, 0);
        }
    }

    // C/D layout: col(o) = lane&15, row(b) = quad*4 + reg.
    // 0.5f compensates the doubled K-loop (exact).
    const float s = 0.5f * scale[o];
    const int b0 = quad * 4;
#pragma unroll
    for (int r = 0; r < 4; ++r) {
        unsafeAtomicAdd(out + (size_t)(b0 + r)      * OUT_N + o, s * acc0[r]);
        unsafeAtomicAdd(out + (size_t)(b0 + r + 16) * OUT_N + o, s * acc1[r]);
    }
}

extern "C" void kernel_launch(void* const* d_in, const int* in_sizes, int n_in,
                              void* d_out, int out_size, void* d_ws, size_t ws_size,
                              hipStream_t stream) {
    const float* x     = (const float*)d_in[0];
    const int*   wq    = (const int*)d_in[1];
    const float* scale = (const float*)d_in[2];
    const float* bias  = (const float*)d_in[3];
    float* out = (float*)d_out;

    init_kernel<<<dim3((BATCH * OUT_N + 255) / 256), 256, 0, stream>>>(bias, out);
    lin2bit_kernel<<<dim3(OUT_N / OPB, SEGS), 256, 0, stream>>>(wq, scale, x, out);
}

// Round 7
// 265.474 us; speedup vs baseline: 1.2883x; 1.2883x over previous
//
#include <hip/hip_runtime.h>

#define OUT_N 11008
#define IN_K  4096
#define BATCH 32
#define SEGS  8
#define KSEG  (IN_K / SEGS)   // 512 k per block
#define CK    64              // k per double-buffered DMA chunk
#define NCH   (KSEG / CK)     // 8 chunks
#define OPB   64              // outputs per block (4 waves x 16 rows)
#define XSTR  520             // xs row stride (shorts)

typedef __attribute__((ext_vector_type(8))) short short8;
typedef __attribute__((ext_vector_type(4))) float float4v;
typedef __attribute__((address_space(3))) unsigned lds_u32;
typedef __attribute__((address_space(1))) const unsigned glb_u32;

// out[b][o] = bias[o]; main kernel atomically accumulates K-segment partials.
__global__ __launch_bounds__(256) void init_kernel(
    const float* __restrict__ bias, float* __restrict__ out)
{
    int i = blockIdx.x * 256 + threadIdx.x;
    if (i < BATCH * OUT_N) out[i] = bias[i % OUT_N];
}

// fp32 -> bf16 RNE
__device__ __forceinline__ unsigned short f2bf(float f) {
    unsigned u = __builtin_bit_cast(unsigned, f);
    unsigned r = u + 0x7FFFu + ((u >> 16) & 1u);
    return (unsigned short)(r >> 16);
}

// pack two fp32 (exact {-1,0,1}) into two bf16 by mantissa truncation
__device__ __forceinline__ unsigned pkbf16(float fhi, float flo) {
    return __builtin_amdgcn_perm(__builtin_bit_cast(unsigned, fhi),
                                 __builtin_bit_cast(unsigned, flo),
                                 0x07060302u);
}

// Barrier-free K-loop: wave w stages ONLY its own 16 weight rows via async
// global_load_lds (width 16: 1 KB/inst, 4 insts/chunk), double-buffered, and
// is the sole consumer -> no __syncthreads in the loop; 8 waves/CU free-run
// so the CU issues DMA continuously. Per-row rotation swizzle is folded into
// the per-lane GLOBAL address (LDS side is wave-uniform-base + lane*16, rigid):
// LDS slot s of row r holds global int4-group (s + r) & 15 -> consumer b128
// reads spread uniformly over banks.
__global__ __launch_bounds__(256, 2) void lin2bit_kernel(
    const int* __restrict__ wq, const float* __restrict__ scale,
    const float* __restrict__ x, float* __restrict__ out)
{
    __shared__ __align__(16) unsigned short xs[BATCH][XSTR]; // 33280 B
    __shared__ __align__(16) int wl[2][OPB * CK];            // 32768 B -> 2 blk/CU

    const int t    = threadIdx.x;
    const int lane = t & 63;
    const int wave = t >> 6;
    const int kseg = blockIdx.y * KSEG;
    const int o0   = blockIdx.x * OPB;

    // --- W DMA setup: inst j covers rows wave*16+4j .. +3 (1 KB contiguous LDS)
    const int rl   = lane >> 4;   // row within 4-row group
    const int slot = lane & 15;   // int4-group slot within row
    const int* gbase = wq + (size_t)(o0 + wave * 16 + rl) * IN_K + kseg;
    int grot[4];
#pragma unroll
    for (int j = 0; j < 4; ++j) grot[j] = ((slot + 4 * j + rl) & 15) * 4;

#define WISSUE(c, buf)                                                         \
    {                                                                          \
        _Pragma("unroll")                                                      \
        for (int j = 0; j < 4; ++j) {                                          \
            const int* gp = gbase + (size_t)(4 * j) * IN_K + (c) * CK + grot[j]; \
            __builtin_amdgcn_global_load_lds((glb_u32*)gp,                     \
                (lds_u32*)&wl[buf][(wave * 16 + 4 * j) * CK], 16, 0, 0);       \
        }                                                                      \
    }

    WISSUE(0, 0);          // chunks 0/1 fly while xs stages
    WISSUE(1, 1);

    // --- stage x[0:32][kseg:+512] fp32 -> bf16 LDS (16 float4 per thread) ---
#pragma unroll
    for (int it = 0; it < 16; ++it) {
        int idx = it * 256 + t;
        int b   = idx >> 7;            // 128 float4 per row
        int k4  = idx & 127;
        float4 v = *reinterpret_cast<const float4*>(x + b * IN_K + kseg + k4 * 4);
        ushort4 h = { f2bf(v.x), f2bf(v.y), f2bf(v.z), f2bf(v.w) };
        *reinterpret_cast<ushort4*>(&xs[b][k4 * 4]) = h;
    }
    __syncthreads();   // xs visible; also drains chunk-0/1 DMA (warm start)

    // --- compute setup ---
    const int quad = lane >> 4;
    const int l16  = lane & 15;
    const int o    = o0 + wave * 16 + l16;

    const int* wrow = &wl[0][0] + (wave * 16 + l16) * CK;
    const unsigned short* x0 = &xs[l16][quad * 8];
    const unsigned short* x1 = &xs[l16 + 16][quad * 8];
    int woff[2][2];
#pragma unroll
    for (int kt = 0; kt < 2; ++kt)
#pragma unroll
        for (int jj = 0; jj < 2; ++jj)
            woff[kt][jj] = ((kt * 8 + quad * 2 + jj - l16) & 15) * 4;

    float4v acc0 = {0.f, 0.f, 0.f, 0.f};
    float4v acc1 = {0.f, 0.f, 0.f, 0.f};

#define WCOMPUTE(c)                                                            \
    {                                                                          \
        const int* wr = wrow + ((c) & 1) * (OPB * CK);                         \
        _Pragma("unroll")                                                      \
        for (int kt = 0; kt < 2; ++kt) {                                       \
            int4 w0 = *reinterpret_cast<const int4*>(wr + woff[kt][0]);        \
            int4 w1 = *reinterpret_cast<const int4*>(wr + woff[kt][1]);        \
            uint4 bw;                                                          \
            bw.x = pkbf16((float)w0.y, (float)w0.x);                           \
            bw.y = pkbf16((float)w0.w, (float)w0.z);                           \
            bw.z = pkbf16((float)w1.y, (float)w1.x);                           \
            bw.w = pkbf16((float)w1.w, (float)w1.z);                           \
            short8 bf = __builtin_bit_cast(short8, bw);                        \
            short8 a0 = *reinterpret_cast<const short8*>(x0 + (c) * CK + kt * 32); \
            short8 a1 = *reinterpret_cast<const short8*>(x1 + (c) * CK + kt * 32); \
            acc0 = __builtin_amdgcn_mfma_f32_16x16x32_bf16(a0, bf, acc0, 0, 0, 0); \
            acc1 = __builtin_amdgcn_mfma_f32_16x16x32_bf16(a1, bf, acc1, 0, 0, 0); \
        }                                                                      \
    }

    // Barrier-free pipelined K-loop: chunk c consumed while c+1 in flight.
    // vmcnt(4) = wait for chunk c's 4 DMAs (oldest), allow c+1's 4 pending.
#pragma unroll 1
    for (int c = 0; c < NCH - 1; ++c) {
        asm volatile("s_waitcnt vmcnt(4)" ::: "memory");
        WCOMPUTE(c);
        if (c + 2 < NCH) {
            asm volatile("s_waitcnt lgkmcnt(0)" ::: "memory"); // ds_reads landed
            WISSUE(c + 2, (c & 1));                            // refill freed buf
        }
    }
    asm volatile("s_waitcnt vmcnt(0)" ::: "memory");
    WCOMPUTE(NCH - 1);
#undef WISSUE
#undef WCOMPUTE

    // C/D layout: col(o) = lane&15, row(b) = quad*4 + reg
    const float s = scale[o];
    const int b0 = quad * 4;
#pragma unroll
    for (int r = 0; r < 4; ++r) {
        unsafeAtomicAdd(out + (size_t)(b0 + r)      * OUT_N + o, s * acc0[r]);
        unsafeAtomicAdd(out + (size_t)(b0 + r + 16) * OUT_N + o, s * acc1[r]);
    }
}

extern "C" void kernel_launch(void* const* d_in, const int* in_sizes, int n_in,
                              void* d_out, int out_size, void* d_ws, size_t ws_size,
                              hipStream_t stream) {
    const float* x     = (const float*)d_in[0];
    const int*   wq    = (const int*)d_in[1];
    const float* scale = (const float*)d_in[2];
    const float* bias  = (const float*)d_in[3];
    float* out = (float*)d_out;

    init_kernel<<<dim3((BATCH * OUT_N + 255) / 256), 256, 0, stream>>>(bias, out);
    lin2bit_kernel<<<dim3(OUT_N / OPB, SEGS), 256, 0, stream>>>(wq, scale, x, out);
}

// Round 9
// 255.012 us; speedup vs baseline: 1.3412x; 1.0410x over previous
//
#include <hip/hip_runtime.h>

#define OUT_N 11008
#define IN_K  4096
#define BATCH 32
#define SEGS  16
#define KSEG  (IN_K / SEGS)   // 256 k per block
#define OPB   64              // outputs per block (4 waves x 16 rows)
#define XSTR  264             // xs row stride (shorts): 132 words %32=4, 0 conflicts measured (R2)

typedef __attribute__((ext_vector_type(8))) short short8;
typedef __attribute__((ext_vector_type(4))) float float4v;
typedef __attribute__((ext_vector_type(4))) int int4v;   // nt-load-compatible

// out[b][o] = bias[o]; main kernel atomically accumulates K-segment partials.
__global__ __launch_bounds__(256) void init_kernel(
    const float* __restrict__ bias, float* __restrict__ out)
{
    int i = blockIdx.x * 256 + threadIdx.x;
    if (i < BATCH * OUT_N) out[i] = bias[i % OUT_N];
}

// fp32 -> bf16 RNE
__device__ __forceinline__ unsigned short f2bf(float f) {
    unsigned u = __builtin_bit_cast(unsigned, f);
    unsigned r = u + 0x7FFFu + ((u >> 16) & 1u);
    return (unsigned short)(r >> 16);
}

// pack two fp32 (exact {-1,0,1}) into two bf16 by mantissa truncation
__device__ __forceinline__ unsigned pkbf16(float fhi, float flo) {
    return __builtin_amdgcn_perm(__builtin_bit_cast(unsigned, fhi),
                                 __builtin_bit_cast(unsigned, flo),
                                 0x07060302u);
}

// MAX-OCCUPANCY variant: only xs in LDS (16.9 KB) + launch_bounds(256,8)
// -> 8 blocks/CU = 32 waves/CU (vs ~10 in all prior rounds), tripling the
// CU-level outstanding-request pool. Weights stream global->VGPR via
// NON-TEMPORAL dwordx4 (zero reuse; avoids allocating into poison-dirty
// L2/L3 -> no dirty-eviction writeback shadowing the read stream).
__global__ __launch_bounds__(256, 8) void lin2bit_kernel(
    const int* __restrict__ wq, const float* __restrict__ scale,
    const float* __restrict__ x, float* __restrict__ out)
{
    __shared__ unsigned short xs[BATCH][XSTR];   // 16896 B -> 8 blocks/CU

    const int t    = threadIdx.x;
    const int lane = t & 63;
    const int wave = t >> 6;
    const int kseg = blockIdx.y * KSEG;
    const int o0   = blockIdx.x * OPB;

    // --- stage x[0:32][kseg:+256] fp32 -> bf16 LDS (8 float4 per thread) ---
#pragma unroll
    for (int it = 0; it < 8; ++it) {
        int idx = it * 256 + t;
        int b   = idx >> 6;            // 64 float4 per row
        int k4  = idx & 63;
        float4 v = *reinterpret_cast<const float4*>(x + b * IN_K + kseg + k4 * 4);
        ushort4 h = { f2bf(v.x), f2bf(v.y), f2bf(v.z), f2bf(v.w) };
        *reinterpret_cast<ushort4*>(&xs[b][k4 * 4]) = h;
    }
    __syncthreads();

    const int quad = lane >> 4;
    const int l16  = lane & 15;
    const int o    = o0 + wave * 16 + l16;

    const int* __restrict__ wp = wq + (size_t)o * IN_K + kseg + quad * 8;
    const unsigned short* x0 = &xs[l16][quad * 8];
    const unsigned short* x1 = &xs[l16 + 16][quad * 8];

    float4v acc0 = {0.f, 0.f, 0.f, 0.f};
    float4v acc1 = {0.f, 0.f, 0.f, 0.f};

#pragma unroll
    for (int ki = 0; ki < KSEG; ki += 32) {
        int4v w0 = __builtin_nontemporal_load(reinterpret_cast<const int4v*>(wp + ki));
        int4v w1 = __builtin_nontemporal_load(reinterpret_cast<const int4v*>(wp + ki + 4));
        uint4 bw;
        bw.x = pkbf16((float)w0.y, (float)w0.x);
        bw.y = pkbf16((float)w0.w, (float)w0.z);
        bw.z = pkbf16((float)w1.y, (float)w1.x);
        bw.w = pkbf16((float)w1.w, (float)w1.z);
        short8 bf = __builtin_bit_cast(short8, bw);
        short8 a0 = *reinterpret_cast<const short8*>(x0 + ki);
        short8 a1 = *reinterpret_cast<const short8*>(x1 + ki);
        acc0 = __builtin_amdgcn_mfma_f32_16x16x32_bf16(a0, bf, acc0, 0, 0, 0);
        acc1 = __builtin_amdgcn_mfma_f32_16x16x32_bf16(a1, bf, acc1, 0, 0, 0);
    }

    // C/D layout: col(o) = lane&15, row(b) = quad*4 + reg
    const float s = scale[o];
    const int b0 = quad * 4;
#pragma unroll
    for (int r = 0; r < 4; ++r) {
        unsafeAtomicAdd(out + (size_t)(b0 + r)      * OUT_N + o, s * acc0[r]);
        unsafeAtomicAdd(out + (size_t)(b0 + r + 16) * OUT_N + o, s * acc1[r]);
    }
}

extern "C" void kernel_launch(void* const* d_in, const int* in_sizes, int n_in,
                              void* d_out, int out_size, void* d_ws, size_t ws_size,
                              hipStream_t stream) {
    const float* x     = (const float*)d_in[0];
    const int*   wq    = (const int*)d_in[1];
    const float* scale = (const float*)d_in[2];
    const float* bias  = (const float*)d_in[3];
    float* out = (float*)d_out;

    init_kernel<<<dim3((BATCH * OUT_N + 255) / 256), 256, 0, stream>>>(bias, out);
    lin2bit_kernel<<<dim3(OUT_N / OPB, SEGS), 256, 0, stream>>>(wq, scale, x, out);
}